// Round 9
// baseline (215.044 us; speedup 1.0000x reference)
//
#include <hip/hip_runtime.h>
#include <hip/hip_bf16.h>

typedef unsigned int u32;
typedef unsigned short u16;
typedef __attribute__((ext_vector_type(8))) short bf16x8;   // 8 x bf16 (4 VGPR)
typedef __attribute__((ext_vector_type(4))) float f32x4;
typedef __attribute__((ext_vector_type(2))) u32 u32x2;
typedef __attribute__((ext_vector_type(4))) u32 u32x4;

#define LOG2E 1.4426950408889634f
#define SCALE 0.17677669529663687f   /* 32^-0.5 */

__device__ __forceinline__ u16 f2bf(float f) {
    return __builtin_bit_cast(u16, __float2bfloat16(f));    // native cvt, RNE
}
__device__ __forceinline__ u32 pkbf(float a, float b) {
    return (u32)f2bf(a) | ((u32)f2bf(b) << 16);
}
// Pack two f32x4 half-fragments into one K=32 bf16x8 fragment.
// K-permutation pi(8g+i) = 4g+(i&3)+16*(i>=4): valid because BOTH operands of
// every MFMA below are packed with the same pi (dot products are K-perm invariant).
__device__ __forceinline__ bf16x8 pk8(f32x4 a, f32x4 b) {
    u32x4 p = {pkbf(a[0], a[1]), pkbf(a[2], a[3]), pkbf(b[0], b[1]), pkbf(b[2], b[3])};
    return __builtin_bit_cast(bf16x8, p);
}

// XOR-swizzled element index for [rows][128] bf16 LDS tile
__device__ __forceinline__ int sw128(int r, int e) { return r * 128 + (e ^ ((r & 7) << 3)); }

__global__ __launch_bounds__(256) void prep_kernel(
    const float* __restrict__ Wq, const float* __restrict__ Wk,
    const float* __restrict__ Wv, const float* __restrict__ Wo,
    const float* __restrict__ bias_table, const int* __restrict__ rel_index,
    u16* __restrict__ wsW, float* __restrict__ wsB)
{
    int idx = blockIdx.x * 256 + threadIdx.x;
    if (idx < 16384) {
        wsW[idx]         = f2bf(Wq[idx] * (SCALE * LOG2E));  // fold scale*log2e into Wq
        wsW[16384 + idx] = f2bf(Wk[idx]);
        wsW[32768 + idx] = f2bf(Wv[idx]);
        wsW[49152 + idx] = f2bf(Wo[idx]);
        // bias laid out so the QK^T MFMA C-init is one dwordx4 per lane:
        // wsB[(((h*4+mt)*4+nt)*64 + lane)*4 + r] = bias[h][kk=16mt+4g+r][q=16nt+c] * LOG2E
        int h = idx >> 12, t = (idx >> 8) & 15, l = (idx >> 2) & 63, r = idx & 3;
        int mt = t >> 2, nt = t & 3, g = l >> 4, c = l & 15;
        int kk = 16 * mt + 4 * g + r, q = 16 * nt + c;
        wsB[idx] = bias_table[rel_index[q * 64 + kk] * 4 + h] * LOG2E;
    }
}

// LDS: 16 KB total. Xs = x tile 64x128 bf16; after a barrier the SAME region
// becomes hc (head-concat). No registers span the overwrite (x fragments are
// re-read per projection and die before the barrier) -> no remat spills (R6 lesson).
__global__ __launch_bounds__(256, 4) void wattn_kernel(
    const float* __restrict__ x,
    const float* __restrict__ bq, const float* __restrict__ bk,
    const float* __restrict__ bv, const float* __restrict__ bo,
    const u16* __restrict__ Wbf, const float* __restrict__ biasT,
    float* __restrict__ out)
{
    __shared__ u16 smem[8192];   // 16 KB

    const int b    = blockIdx.x;
    const int tid  = threadIdx.x;
    const int wid  = tid >> 6;
    const int lane = tid & 63;
    const int g    = lane >> 4;
    const int c    = lane & 15;
    const int h    = wid;

    u16* Xs = smem;   // x tile; later hc

    // ---- stage x -> LDS bf16 (coalesced, non-temporal: keep L2 for weights) ----
    {
        const float* xb = x + (size_t)b * 8192;
        #pragma unroll
        for (int it = 0; it < 8; ++it) {
            int idx = it * 1024 + tid * 4;
            f32x4 v = __builtin_nontemporal_load((const f32x4*)(xb + idx));
            int row = idx >> 7, col = idx & 127;
            u32x2 wv;
            wv.x = pkbf(v[0], v[1]);
            wv.y = pkbf(v[2], v[3]);
            *(u32x2*)&Xs[sw128(row, col)] = wv;
        }
    }
    __syncthreads();

    // ---- q,k projections, output-transposed D[ch][tok] (R4-verified orientation).
    //      x fragments re-read per kt so they never co-live with accS. ----
    f32x4 accQ[2][4], accK[2][4];
    #pragma unroll
    for (int CT = 0; CT < 2; ++CT) {
        float4 bbq = *(const float4*)&bq[32 * h + 16 * CT + 4 * g];
        float4 bbk = *(const float4*)&bk[32 * h + 16 * CT + 4 * g];
        f32x4 qi = {bbq.x * (SCALE * LOG2E), bbq.y * (SCALE * LOG2E),
                    bbq.z * (SCALE * LOG2E), bbq.w * (SCALE * LOG2E)};
        f32x4 ki = {bbk.x, bbk.y, bbk.z, bbk.w};
        #pragma unroll
        for (int nt = 0; nt < 4; ++nt) { accQ[CT][nt] = qi; accK[CT][nt] = ki; }
    }
    #pragma unroll
    for (int kt = 0; kt < 4; ++kt) {
        bf16x8 xt[4];
        #pragma unroll
        for (int nt = 0; nt < 4; ++nt)
            xt[nt] = *(const bf16x8*)&Xs[sw128(16 * nt + c, 32 * kt + 8 * g)];
        #pragma unroll
        for (int CT = 0; CT < 2; ++CT) {
            bf16x8 wq = *(const bf16x8*)(Wbf + (32 * h + 16 * CT + c) * 128 + 32 * kt + 8 * g);
            bf16x8 wk = *(const bf16x8*)(Wbf + 16384 + (32 * h + 16 * CT + c) * 128 + 32 * kt + 8 * g);
            #pragma unroll
            for (int nt = 0; nt < 4; ++nt) {
                accQ[CT][nt] = __builtin_amdgcn_mfma_f32_16x16x32_bf16(wq, xt[nt], accQ[CT][nt], 0, 0, 0);
                accK[CT][nt] = __builtin_amdgcn_mfma_f32_16x16x32_bf16(wk, xt[nt], accK[CT][nt], 0, 0, 0);
            }
        }
    }
    // pack to K=32 fragments under pi (k-elems = channels {4g..4g+3, 16+4g..+3})
    bf16x8 qf8[4], kf8[4];
    #pragma unroll
    for (int nt = 0; nt < 4; ++nt) {
        qf8[nt] = pk8(accQ[0][nt], accQ[1][nt]);
        kf8[nt] = pk8(accK[0][nt], accK[1][nt]);
    }

    // ---- QK^T, all-register: accS[mt][nt] = S^T[kk 16mt+..][q 16nt+..] + bias ----
    f32x4 accS[4][4];
    {
        const f32x4* bT = (const f32x4*)(biasT + h * 4096);
        #pragma unroll
        for (int mt = 0; mt < 4; ++mt)
            #pragma unroll
            for (int nt = 0; nt < 4; ++nt)
                accS[mt][nt] = __builtin_amdgcn_mfma_f32_16x16x32_bf16(
                    kf8[mt], qf8[nt], bT[(mt * 4 + nt) * 64 + lane], 0, 0, 0);
    }

    // ---- softmax over kk (rows of S^T); scale P by 1/sum BEFORE pack (exact ref) ----
    #pragma unroll
    for (int nt = 0; nt < 4; ++nt) {
        float m = accS[0][nt][0];
        #pragma unroll
        for (int mt = 0; mt < 4; ++mt)
            #pragma unroll
            for (int r = 0; r < 4; ++r) m = fmaxf(m, accS[mt][nt][r]);
        m = fmaxf(m, __shfl_xor(m, 16, 64));
        m = fmaxf(m, __shfl_xor(m, 32, 64));
        float s = 0.f;
        #pragma unroll
        for (int mt = 0; mt < 4; ++mt)
            #pragma unroll
            for (int r = 0; r < 4; ++r) {
                float e = exp2f(accS[mt][nt][r] - m);
                accS[mt][nt][r] = e;
                s += e;
            }
        s += __shfl_xor(s, 16, 64);
        s += __shfl_xor(s, 32, 64);
        float rinv = 1.0f / s;
        #pragma unroll
        for (int mt = 0; mt < 4; ++mt)
            #pragma unroll
            for (int r = 0; r < 4; ++r) accS[mt][nt][r] *= rinv;
    }
    // P^T A-fragments under pi: pf8[u][nt] covers kk {32u+4g..+3, 32u+16+4g..+3}
    bf16x8 pf8[2][4];
    #pragma unroll
    for (int u = 0; u < 2; ++u)
        #pragma unroll
        for (int nt = 0; nt < 4; ++nt)
            pf8[u][nt] = pk8(accS[2 * u][nt], accS[2 * u + 1][nt]);

    // ---- v projection, standard orientation D[tok][ch] (R5-verified): its D-layout
    //      IS the PV B-fragment after pi-pack. ----
    f32x4 vacc[2][4];
    #pragma unroll
    for (int j = 0; j < 2; ++j) {
        float bc = bv[32 * h + 16 * j + c];
        f32x4 bi = {bc, bc, bc, bc};
        #pragma unroll
        for (int mt = 0; mt < 4; ++mt) vacc[j][mt] = bi;
    }
    #pragma unroll
    for (int kt = 0; kt < 4; ++kt) {
        bf16x8 xt[4];
        #pragma unroll
        for (int mt = 0; mt < 4; ++mt)
            xt[mt] = *(const bf16x8*)&Xs[sw128(16 * mt + c, 32 * kt + 8 * g)];
        #pragma unroll
        for (int j = 0; j < 2; ++j) {
            bf16x8 wv = *(const bf16x8*)(Wbf + 32768 + (32 * h + 16 * j + c) * 128 + 32 * kt + 8 * g);
            #pragma unroll
            for (int mt = 0; mt < 4; ++mt)
                vacc[j][mt] = __builtin_amdgcn_mfma_f32_16x16x32_bf16(xt[mt], wv, vacc[j][mt], 0, 0, 0);
        }
    }
    bf16x8 vf8[2][2];   // [j][u]: kk {32u+4g..+3, 32u+16+4g..+3}, ch col 16j+c
    #pragma unroll
    for (int j = 0; j < 2; ++j)
        #pragma unroll
        for (int u = 0; u < 2; ++u)
            vf8[j][u] = pk8(vacc[j][2 * u], vacc[j][2 * u + 1]);

    // ---- PV, all-register: out[tok][ch] = P^T(A) . V(B) ----
    f32x4 accO[4][2];
    #pragma unroll
    for (int nt = 0; nt < 4; ++nt)
        #pragma unroll
        for (int j = 0; j < 2; ++j) { f32x4 z = {0.f, 0.f, 0.f, 0.f}; accO[nt][j] = z; }
    #pragma unroll
    for (int u = 0; u < 2; ++u)
        #pragma unroll
        for (int nt = 0; nt < 4; ++nt)
            #pragma unroll
            for (int j = 0; j < 2; ++j)
                accO[nt][j] = __builtin_amdgcn_mfma_f32_16x16x32_bf16(
                    pf8[u][nt], vf8[j][u], accO[nt][j], 0, 0, 0);

    __syncthreads();   // all waves done reading Xs -> region becomes hc

    // head output -> hc[tok][ch] (lane holds out[16nt+4g+r][16j+c] of its head)
    #pragma unroll
    for (int nt = 0; nt < 4; ++nt)
        #pragma unroll
        for (int j = 0; j < 2; ++j)
            #pragma unroll
            for (int r = 0; r < 4; ++r)
                Xs[sw128(16 * nt + 4 * g + r, 32 * h + 16 * j + c)] = f2bf(accO[nt][j][r]);
    __syncthreads();

    // ---- phase C (R5/R8-proven): out = hc.Wo^T + bo, D[tok][och], scalar dword
    //      non-temporal stores (lane-contiguous) ----
    bf16x8 ha[4][4];
    #pragma unroll
    for (int mt = 0; mt < 4; ++mt)
        #pragma unroll
        for (int kt = 0; kt < 4; ++kt)
            ha[mt][kt] = *(const bf16x8*)&Xs[sw128(16 * mt + c, 32 * kt + 8 * g)];
    const u16* Wo_ = Wbf + 49152;
    float* ob = out + (size_t)b * 8192;
    #pragma unroll
    for (int j = 0; j < 2; ++j) {
        int OT = 2 * wid + j;
        float bocol = bo[16 * OT + c];
        f32x4 acc[4];
        #pragma unroll
        for (int mt = 0; mt < 4; ++mt) { f32x4 t = {bocol, bocol, bocol, bocol}; acc[mt] = t; }
        const u16* W = Wo_ + (16 * OT + c) * 128;
        #pragma unroll
        for (int kt = 0; kt < 4; ++kt) {
            bf16x8 wf = *(const bf16x8*)(W + 32 * kt + 8 * g);
            #pragma unroll
            for (int mt = 0; mt < 4; ++mt)
                acc[mt] = __builtin_amdgcn_mfma_f32_16x16x32_bf16(ha[mt][kt], wf, acc[mt], 0, 0, 0);
        }
        #pragma unroll
        for (int mt = 0; mt < 4; ++mt)
            #pragma unroll
            for (int r = 0; r < 4; ++r)
                __builtin_nontemporal_store(acc[mt][r],
                    &ob[(16 * mt + 4 * g + r) * 128 + 16 * OT + c]);
    }
}

extern "C" void kernel_launch(void* const* d_in, const int* in_sizes, int n_in,
                              void* d_out, int out_size, void* d_ws, size_t ws_size,
                              hipStream_t stream)
{
    const float* query      = (const float*)d_in[0];
    const float* Wq         = (const float*)d_in[1];
    const float* bq         = (const float*)d_in[2];
    const float* Wk         = (const float*)d_in[3];
    const float* bk         = (const float*)d_in[4];
    const float* Wv         = (const float*)d_in[5];
    const float* bv         = (const float*)d_in[6];
    const float* Wo         = (const float*)d_in[7];
    const float* bo         = (const float*)d_in[8];
    const float* bias_table = (const float*)d_in[9];
    const int*   rel_index  = (const int*)d_in[10];

    u16*   wsW = (u16*)d_ws;                          // 4 x 32 KB bf16 weights
    float* wsB = (float*)((char*)d_ws + 131072);      // bias, MFMA-C-init layout, 64 KB

    prep_kernel<<<dim3(64), dim3(256), 0, stream>>>(Wq, Wk, Wv, Wo, bias_table, rel_index, wsW, wsB);
    wattn_kernel<<<dim3(4096), dim3(256), 0, stream>>>(query, bq, bk, bv, bo, wsW, wsB, (float*)d_out);
}